// Round 1
// baseline (995.902 us; speedup 1.0000x reference)
//
#include <hip/hip_runtime.h>
#include <hip/hip_bf16.h>

// ---------------- problem constants ----------------
#define NLAY 4
#define DH   512
#define NST  64
#define NB   16
#define SL   2048
#define NDO  256
#define BL   (NB*SL)      // 32768 rows
#define KDIM 512
#define TWOPI 6.283185307179586476925287

typedef unsigned short u16;
typedef __attribute__((ext_vector_type(8))) short  short8v;   // 8 bf16 (4 VGPR) MFMA frag
typedef __attribute__((ext_vector_type(8))) unsigned short ushort8v;
typedef __attribute__((ext_vector_type(4))) float  f32x4;

// ---------------- small helpers ----------------
__device__ __forceinline__ float bf2f(u16 v){
  union { unsigned u; float f; } x; x.u = ((unsigned)v) << 16; return x.f;
}
__device__ __forceinline__ u16 f2bf(float f){
  union { float f; unsigned u; } x; x.f = f;
  unsigned u = x.u;
  unsigned r = u + 0x7fffu + ((u >> 16) & 1u);   // RNE
  return (u16)(r >> 16);
}
__device__ __forceinline__ void cmulw(float& xr, float& xi, float wr, float wi){
  float tr = xr*wr - xi*wi;
  xi = fmaf(xr, wi, xi*wr);
  xr = tr;
}
__device__ __forceinline__ float gelu_tanh(float v){
  const float c0 = 0.7978845608028654f;
  float u = c0 * fmaf(0.044715f, v*v*v, v);
  return 0.5f * v * (1.0f + tanhf(u));
}

// ---------------- DFT-16 in registers (radix-4 x radix-4), natural in/out ----
template<int SGN>
__device__ __forceinline__ void dft4w(float& r0, float& i0, float& r1, float& i1,
                                      float& r2, float& i2, float& r3, float& i3){
  const float t0r = r0 + r2, t0i = i0 + i2;
  const float t1r = r0 - r2, t1i = i0 - i2;
  const float t2r = r1 + r3, t2i = i1 + i3;
  const float t3r = r1 - r3, t3i = i1 - i3;
  r0 = t0r + t2r; i0 = t0i + t2i;
  r2 = t0r - t2r; i2 = t0i - t2i;
  if (SGN < 0){ r1 = t1r + t3i; i1 = t1i - t3r; r3 = t1r - t3i; i3 = t1i + t3r; }
  else        { r1 = t1r - t3i; i1 = t1i + t3r; r3 = t1r + t3i; i3 = t1i - t3r; }
}

template<int SGN>
__device__ __forceinline__ void dft16(float* re, float* im){
#pragma unroll
  for (int b = 0; b < 4; b++)
    dft4w<SGN>(re[b], im[b], re[4+b], im[4+b], re[8+b], im[8+b], re[12+b], im[12+b]);
  const float C1 = 0.92387953251128675613f, S1_ = 0.38268343236508977172f;
  const float C2 = 0.70710678118654752440f;
  const float sg = (SGN < 0) ? -1.f : 1.f;
  cmulw(re[5],  im[5],   C1,  sg*S1_);
  cmulw(re[9],  im[9],   C2,  sg*C2);
  cmulw(re[13], im[13],  S1_, sg*C1);
  cmulw(re[6],  im[6],   C2,  sg*C2);
  cmulw(re[10], im[10],  0.f, sg*1.f);
  cmulw(re[14], im[14], -C2,  sg*C2);
  cmulw(re[7],  im[7],   S1_, sg*C1);
  cmulw(re[11], im[11], -C2,  sg*C2);
  cmulw(re[15], im[15], -C1,  sg*(-S1_));
#pragma unroll
  for (int c = 0; c < 4; c++)
    dft4w<SGN>(re[4*c], im[4*c], re[4*c+1], im[4*c+1], re[4*c+2], im[4*c+2], re[4*c+3], im[4*c+3]);
  // un-permute base-4 digit reversal (X[c+4d] currently at slot 4c+d)
  float tr_, ti_;
#define SWP(A,B) tr_=re[A]; re[A]=re[B]; re[B]=tr_; ti_=im[A]; im[A]=im[B]; im[B]=ti_;
  SWP(1,4) SWP(2,8) SWP(3,12) SWP(6,9) SWP(7,13) SWP(11,14)
#undef SWP
}

// LDS padding: all three stage patterns <=2-way bank conflicts
__device__ __forceinline__ int cxpad(int i){ return i + (i >> 4) + ((i >> 8) << 1); }
#define CXSZ 4384

// forward 4096-pt DIF radix-16: input x[t+256j] in re/im, output (digit-reversed
// ownership): thread t holds bins at positions 16t+k3
__device__ __forceinline__ void fwd4096(float* re, float* im, float2* cx, int t){
  dft16<-1>(re, im);
  const float a0 = -(float)(TWOPI/4096.0) * (float)t;
#pragma unroll
  for (int k = 0; k < 16; k++){
    if (k){ float sn = __sinf(a0*(float)k), cs = __cosf(a0*(float)k); cmulw(re[k], im[k], cs, sn); }
    cx[cxpad(t + 256*k)] = make_float2(re[k], im[k]);
  }
  __syncthreads();
  const int k1 = t >> 4, m2 = t & 15;
  const int b2 = k1*256 + m2;
#pragma unroll
  for (int j = 0; j < 16; j++){ float2 v = cx[cxpad(b2 + 16*j)]; re[j] = v.x; im[j] = v.y; }
  dft16<-1>(re, im);
  const float b0 = -(float)(TWOPI/256.0) * (float)m2;
#pragma unroll
  for (int k = 0; k < 16; k++){
    if (k){ float sn = __sinf(b0*(float)k), cs = __cosf(b0*(float)k); cmulw(re[k], im[k], cs, sn); }
    cx[cxpad(b2 + 16*k)] = make_float2(re[k], im[k]);
  }
  __syncthreads();
#pragma unroll
  for (int j = 0; j < 16; j++){ float2 v = cx[cxpad(16*t + j)]; re[j] = v.x; im[j] = v.y; }
  dft16<-1>(re, im);   // X[k3] in re/im
}

// inverse: input = values at positions 16t+k3, output time y[t+256j] (unscaled)
__device__ __forceinline__ void inv4096(float* re, float* im, float2* cx, int t){
  dft16<1>(re, im);
#pragma unroll
  for (int j = 0; j < 16; j++) cx[cxpad(16*t + j)] = make_float2(re[j], im[j]);
  __syncthreads();
  const int k1 = t >> 4, m2 = t & 15;
  const int b2 = k1*256 + m2;
  const float b0 = (float)(TWOPI/256.0) * (float)m2;
#pragma unroll
  for (int k = 0; k < 16; k++){
    float2 v = cx[cxpad(b2 + 16*k)];
    re[k] = v.x; im[k] = v.y;
    if (k){ float sn = __sinf(b0*(float)k), cs = __cosf(b0*(float)k); cmulw(re[k], im[k], cs, sn); }
  }
  dft16<1>(re, im);
#pragma unroll
  for (int j = 0; j < 16; j++) cx[cxpad(b2 + 16*j)] = make_float2(re[j], im[j]);
  __syncthreads();
  const float a0 = (float)(TWOPI/4096.0) * (float)t;
#pragma unroll
  for (int k = 0; k < 16; k++){
    float2 v = cx[cxpad(t + 256*k)];
    re[k] = v.x; im[k] = v.y;
    if (k){ float sn = __sinf(a0*(float)k), cs = __cosf(a0*(float)k); cmulw(re[k], im[k], cs, sn); }
  }
  dft16<1>(re, im);
}

// ---------------- generic f32 -> bf16 convert ----------------
__global__ __launch_bounds__(256) void f32_to_bf16_k(const float* __restrict__ src,
                                                     u16* __restrict__ dst, int n8){
  int i = blockIdx.x * 256 + threadIdx.x;
  if (i >= n8) return;
  const float4* s = ((const float4*)src) + 2*(size_t)i;
  float4 a = s[0], b = s[1];
  ushort8v o;
  o[0]=f2bf(a.x); o[1]=f2bf(a.y); o[2]=f2bf(a.z); o[3]=f2bf(a.w);
  o[4]=f2bf(b.x); o[5]=f2bf(b.y); o[6]=f2bf(b.z); o[7]=f2bf(b.w);
  ((ushort8v*)dst)[i] = o;
}

// ---------------- kernel A: DPLR generating function -> Kd (digit-rev order) --
__global__ __launch_bounds__(256) void kd_kernel(
  const float* __restrict__ lam_re, const float* __restrict__ lam_im,
  const float* __restrict__ p_re,  const float* __restrict__ p_im,
  const float* __restrict__ b_re,  const float* __restrict__ b_im,
  const float* __restrict__ c_re,  const float* __restrict__ c_im,
  const float* __restrict__ lstep, float2* __restrict__ Kd)
{
  __shared__ float2 cons[5][NST];
  __shared__ float  ar[SL], ai[SL];
  __shared__ float2 cx[CXSZ];
  const int t = threadIdx.x;
  const int wg = blockIdx.x, lay = wg >> 9, h = wg & 511;

  if (t < NST){
    const int idx = (lay*DH + h)*NST + t;
    const float lr = lam_re[idx], li = lam_im[idx];
    const float pr = p_re[idx],  pi = p_im[idx];
    const float br = b_re[idx],  bi = b_im[idx];
    const float cr = c_re[idx],  ci = c_im[idx];
    cons[0][t] = make_float2(lr, li);
    cons[1][t] = make_float2(cr*br + ci*bi, cr*bi - ci*br);   // conj(C)*B
    cons[2][t] = make_float2(cr*pr + ci*pi, cr*pi - ci*pr);   // conj(C)*P
    cons[3][t] = make_float2(pr*br + pi*bi, pr*bi - pi*br);   // conj(P)*B
    cons[4][t] = make_float2(pr*pr + pi*pi, 0.f);             // conj(P)*P (real)
  }
  const float stp = expf(lstep[lay*DH + h]);
  const float tw0 = 2.0f / stp;
  __syncthreads();

  // --- Cauchy sums -> at_roots, scattered to bit-reversed positions ---
  for (int q = 0; q < 8; q++){
    const int l = t + 256*q;
    const float th = (float)(TWOPI/2048.0) * (float)l;
    const float sn = sinf(th), cs = cosf(th);   // precise (l=1024 near-singular)
    const float omr = cs, omi = -sn;            // Omega = exp(-i th)
    const float a1r = 1.f - omr, a1i = -omi;    // 1 - Omega
    const float a2r = 1.f + omr, a2i =  omi;    // 1 + Omega
    const float inv2 = 1.0f / fmaf(a2r, a2r, a2i*a2i);
    const float gr = tw0 * fmaf(a1r, a2r,  a1i*a2i) * inv2;
    const float gi = tw0 * fmaf(a1i, a2r, -a1r*a2i) * inv2;
    const float clr = 2.f * a2r * inv2, cli = -2.f * a2i * inv2;   // c = 2/(1+Om)
    float k00r=0.f,k00i=0.f,k01r=0.f,k01i=0.f,k10r=0.f,k10i=0.f,k11r=0.f,k11i=0.f;
    for (int n = 0; n < NST; n++){
      const float2 lm = cons[0][n];
      const float dr = gr - lm.x, di = gi - lm.y;
      const float s = 1.0f / fmaf(dr, dr, di*di);
      const float ivr = dr * s, ivi = -di * s;                // 1/(g-Lam)
      float2 u;
      u = cons[1][n]; k00r = fmaf(u.x,ivr,fmaf(-u.y,ivi,k00r)); k00i = fmaf(u.x,ivi,fmaf(u.y,ivr,k00i));
      u = cons[2][n]; k01r = fmaf(u.x,ivr,fmaf(-u.y,ivi,k01r)); k01i = fmaf(u.x,ivi,fmaf(u.y,ivr,k01i));
      u = cons[3][n]; k10r = fmaf(u.x,ivr,fmaf(-u.y,ivi,k10r)); k10i = fmaf(u.x,ivi,fmaf(u.y,ivr,k10i));
      u = cons[4][n]; k11r = fmaf(u.x,ivr,k11r);                k11i = fmaf(u.x,ivi,k11i);
    }
    const float d1r = 1.f + k11r, d1i = k11i;
    const float idn = 1.0f / fmaf(d1r, d1r, d1i*d1i);
    const float wr = k01r*k10r - k01i*k10i, wi = k01r*k10i + k01i*k10r;  // k01*k10
    const float vr = fmaf(wr, d1r,  wi*d1i) * idn;
    const float vi = fmaf(wi, d1r, -wr*d1i) * idn;                       // /(1+k11)
    const float sr = k00r - vr, si = k00i - vi;
    const int brv = __brev((unsigned)l) >> 21;    // 11-bit reverse
    ar[brv] = clr*sr - cli*si;
    ai[brv] = fmaf(clr, si, cli*sr);
  }
  __syncthreads();

  // --- inverse DFT-2048 (radix-2 DIT, bit-reversed input -> natural K) ---
  for (int s = 0; s < 11; s++){
    const int half = 1 << s;
    const float fac = (float)(TWOPI) / (float)(2 << s);
#pragma unroll
    for (int q = 0; q < 4; q++){
      const int v = t + 256*q;
      const int pos = v & (half - 1);
      const int i0 = ((v >> s) << (s+1)) + pos;
      const int i1 = i0 + half;
      const float ang = fac * (float)pos;
      const float wc = __cosf(ang), ws = __sinf(ang);   // e^{+i ang}
      const float xr = ar[i1], xi = ai[i1];
      const float tr = wc*xr - ws*xi, ti = fmaf(wc, xi, ws*xr);
      const float ur_ = ar[i0], ui_ = ai[i0];
      ar[i0] = ur_ + tr; ai[i0] = ui_ + ti;
      ar[i1] = ur_ - tr; ai[i1] = ui_ - ti;
    }
    __syncthreads();
  }

  // --- K (real, scaled 1/2048), zero-pad to 4096, forward DIF -> Kd ---
  float re[16], im[16];
#pragma unroll
  for (int j = 0; j < 16; j++){
    re[j] = (j < 8) ? ar[t + 256*j] * (1.0f/2048.f) : 0.f;
    im[j] = 0.f;
  }
  fwd4096(re, im, cx, t);
  float2* kp = Kd + (size_t)wg * 4096 + 16*t;
#pragma unroll
  for (int k = 0; k < 16; k += 2)
    *(float4*)(kp + k) = make_float4(re[k], im[k], re[k+1], im[k+1]);
}

// ---------------- LayerNorm (f32 in, bf16 out, [b,l,h] layout) ---------------
__global__ __launch_bounds__(256) void ln_k(const float* __restrict__ hsrc,
    const float* __restrict__ gam, const float* __restrict__ bet,
    u16* __restrict__ zdst){
  const int row = blockIdx.x * 4 + (threadIdx.x >> 6);
  const int lane = threadIdx.x & 63;
  const float* p = hsrc + (size_t)row * DH + lane * 8;
  float4 a = *(const float4*)p, b = *(const float4*)(p + 4);
  float s  = (a.x + a.y) + (a.z + a.w) + (b.x + b.y) + (b.z + b.w);
  float sq = a.x*a.x + a.y*a.y + a.z*a.z + a.w*a.w
           + b.x*b.x + b.y*b.y + b.z*b.z + b.w*b.w;
#pragma unroll
  for (int o = 32; o; o >>= 1){ s += __shfl_xor(s, o); sq += __shfl_xor(sq, o); }
  const float mu = s * (1.0f/DH);
  const float rs = rsqrtf(sq * (1.0f/DH) - mu*mu + 1e-6f);
  const float4 g0 = *(const float4*)(gam + lane*8), g1 = *(const float4*)(gam + lane*8 + 4);
  const float4 t0 = *(const float4*)(bet + lane*8), t1 = *(const float4*)(bet + lane*8 + 4);
  ushort8v o;
  o[0] = f2bf(fmaf((a.x - mu)*rs, g0.x, t0.x));
  o[1] = f2bf(fmaf((a.y - mu)*rs, g0.y, t0.y));
  o[2] = f2bf(fmaf((a.z - mu)*rs, g0.z, t0.z));
  o[3] = f2bf(fmaf((a.w - mu)*rs, g0.w, t0.w));
  o[4] = f2bf(fmaf((b.x - mu)*rs, g1.x, t1.x));
  o[5] = f2bf(fmaf((b.y - mu)*rs, g1.y, t1.y));
  o[6] = f2bf(fmaf((b.z - mu)*rs, g1.z, t1.z));
  o[7] = f2bf(fmaf((b.w - mu)*rs, g1.w, t1.w));
  *(ushort8v*)(zdst + (size_t)row * DH + lane*8) = o;
}

// ---------------- bf16 transpose [b,l,h] -> [b,h,l] --------------------------
__global__ __launch_bounds__(256) void transp_k(const u16* __restrict__ z,
                                                u16* __restrict__ zT){
  __shared__ u16 tile[64][72];
  const int bz = blockIdx.z;
  const int l0 = blockIdx.x * 64, h0 = blockIdx.y * 64;
  const int r = threadIdx.x >> 2, c4 = (threadIdx.x & 3) * 16;
  const u16* src = z + ((size_t)bz * SL + l0 + r) * DH + h0 + c4;
  ushort8v v0 = *(const ushort8v*)src;
  ushort8v v1 = *(const ushort8v*)(src + 8);
#pragma unroll
  for (int j = 0; j < 8; j++){ tile[c4 + j][r] = v0[j]; tile[c4 + 8 + j][r] = v1[j]; }
  __syncthreads();
  u16* dst = zT + ((size_t)bz * DH + h0 + r) * SL + l0 + c4;
  ushort8v o0 = *(const ushort8v*)&tile[r][c4];
  ushort8v o1 = *(const ushort8v*)&tile[r][c4 + 8];
  *(ushort8v*)dst = o0;
  *(ushort8v*)(dst + 8) = o1;
}

// ---------------- S4 FFT convolution + D*u + GELU ----------------------------
// One WG convolves TWO batches of the same channel packed as one complex seq
// (K real => re/im parts separate cleanly).
__global__ __launch_bounds__(256) void s4conv_k(
    const u16* __restrict__ zT, const float2* __restrict__ Kd,
    const float* __restrict__ dpar, u16* __restrict__ yT)
{
  __shared__ float2 cx[CXSZ];
  const int t = threadIdx.x;
  const int wg = blockIdx.x;          // 8 pairs * 512 channels
  const int h = wg & 511, bp = wg >> 9;
  const u16* r1 = zT + ((size_t)(2*bp) * DH + h) * SL;
  const u16* r2 = r1 + (size_t)DH * SL;
  float ur1[8], ur2[8];
  float re[16], im[16];
#pragma unroll
  for (int j = 0; j < 8; j++){
    ur1[j] = bf2f(r1[t + 256*j]);
    ur2[j] = bf2f(r2[t + 256*j]);
    re[j] = ur1[j]; im[j] = ur2[j];
  }
#pragma unroll
  for (int j = 8; j < 16; j++){ re[j] = 0.f; im[j] = 0.f; }

  fwd4096(re, im, cx, t);

  const float2* kp = Kd + (size_t)h * 4096 + 16*t;
#pragma unroll
  for (int k = 0; k < 16; k += 2){
    float4 w2 = *(const float4*)(kp + k);
    cmulw(re[k],   im[k],   w2.x, w2.y);
    cmulw(re[k+1], im[k+1], w2.z, w2.w);
  }

  inv4096(re, im, cx, t);

  const float Dv = dpar[h];
  u16* y1 = yT + ((size_t)(2*bp) * DH + h) * SL;
  u16* y2 = y1 + (size_t)DH * SL;
#pragma unroll
  for (int j = 0; j < 8; j++){
    float v1 = fmaf(re[j], (1.0f/4096.f), Dv * ur1[j]);
    float v2 = fmaf(im[j], (1.0f/4096.f), Dv * ur2[j]);
    y1[t + 256*j] = f2bf(gelu_tanh(v1));
    y2[t + 256*j] = f2bf(gelu_tanh(v2));
  }
}

// ---------------- bf16 MFMA GEMM, 128x128 tile, BK=32 ------------------------
// ATRANS: A stored [K][Mb] per batch (blockIdx.z), else [M][K]. W is f32 [K][N],
// converted to bf16 during staging. Optional residual add (in-place safe).
template<bool ATRANS, bool RESID>
__global__ __launch_bounds__(256) void gemm_k(
    const u16* __restrict__ A, const float* __restrict__ W,
    const float* __restrict__ bias,
    const float* __restrict__ resid, float* __restrict__ Cout,
    int Mb, int N)
{
  __shared__ u16 As[128][40];
  __shared__ u16 Bs[128][40];
  const int t = threadIdx.x;
  const int m0 = blockIdx.x * 128, n0 = blockIdx.y * 128, bb = blockIdx.z;
  const int lane = t & 63, wv = t >> 6;
  const int wm = (wv >> 1) * 64, wn = (wv & 1) * 64;
  f32x4 acc[4][4];
#pragma unroll
  for (int mi = 0; mi < 4; mi++)
#pragma unroll
    for (int ni = 0; ni < 4; ni++) acc[mi][ni] = {0.f, 0.f, 0.f, 0.f};

  const size_t Abase = ATRANS ? (size_t)bb * KDIM * Mb : 0;

  for (int k0 = 0; k0 < KDIM; k0 += 32){
    __syncthreads();
    if (ATRANS){
      const int kk = t >> 3, ch = t & 7;
      const u16* srca = A + Abase + (size_t)(k0 + kk) * Mb + m0 + ch*16;
      ushort8v v0 = *(const ushort8v*)srca;
      ushort8v v1 = *(const ushort8v*)(srca + 8);
      const int col = (kk & 7) | (((kk >> 3) ^ (ch & 3)) << 3);
#pragma unroll
      for (int i = 0; i < 8; i++){
        As[ch*16 + i][col]     = (u16)v0[i];
        As[ch*16 + 8 + i][col] = (u16)v1[i];
      }
    } else {
      const int r = t >> 1, kh = (t & 1) << 4;
      const u16* srca = A + (size_t)(m0 + r) * KDIM + k0 + kh;
      ushort8v v0 = *(const ushort8v*)srca;
      ushort8v v1 = *(const ushort8v*)(srca + 8);
      const int s3 = (r >> 4) & 3;
      const int c0 = (((kh >> 3) ^ s3) << 3);
      const int c1 = ((((kh >> 3) + 1) ^ s3) << 3);
      *(ushort8v*)&As[r][c0] = v0;
      *(ushort8v*)&As[r][c1] = v1;
    }
    {
      const int kk = t >> 3, ch = t & 7;
      const float* srcw = W + (size_t)(k0 + kk) * N + n0 + ch*16;
      float4 f0 = *(const float4*)(srcw);
      float4 f1 = *(const float4*)(srcw + 4);
      float4 f2 = *(const float4*)(srcw + 8);
      float4 f3 = *(const float4*)(srcw + 12);
      const int col = (kk & 7) | (((kk >> 3) ^ (ch & 3)) << 3);
      float vv[16] = { f0.x,f0.y,f0.z,f0.w, f1.x,f1.y,f1.z,f1.w,
                       f2.x,f2.y,f2.z,f2.w, f3.x,f3.y,f3.z,f3.w };
#pragma unroll
      for (int i = 0; i < 16; i++) Bs[ch*16 + i][col] = f2bf(vv[i]);
    }
    __syncthreads();

    const int ko = (lane >> 4) * 8;
    const int fr = lane & 15;
    short8v af[4], bf[4];
#pragma unroll
    for (int mi = 0; mi < 4; mi++){
      const int col = (((ko >> 3) ^ (((wm >> 4) + mi) & 3)) << 3);
      af[mi] = *(const short8v*)&As[wm + mi*16 + fr][col];
    }
#pragma unroll
    for (int ni = 0; ni < 4; ni++){
      const int col = (((ko >> 3) ^ (((wn >> 4) + ni) & 3)) << 3);
      bf[ni] = *(const short8v*)&Bs[wn + ni*16 + fr][col];
    }
#pragma unroll
    for (int mi = 0; mi < 4; mi++)
#pragma unroll
      for (int ni = 0; ni < 4; ni++)
        acc[mi][ni] = __builtin_amdgcn_mfma_f32_16x16x32_bf16(af[mi], bf[ni], acc[mi][ni], 0, 0, 0);
  }

  // epilogue: C/D layout col=lane&15, row=(lane>>4)*4+q
  const int fr = lane & 15;
  const int rq = (lane >> 4) * 4;
#pragma unroll
  for (int mi = 0; mi < 4; mi++){
#pragma unroll
    for (int ni = 0; ni < 4; ni++){
      const int gn = n0 + wn + ni*16 + fr;
      const float bs = bias[gn];
#pragma unroll
      for (int q = 0; q < 4; q++){
        const int gm = m0 + wm + mi*16 + rq + q;
        const size_t idx = ((size_t)bb * Mb + gm) * N + gn;
        float v = acc[mi][ni][q] + bs;
        if (RESID) v += resid[idx];
        Cout[idx] = v;
      }
    }
  }
}

// ---------------- in-place log-softmax over rows of 256 ----------------------
__global__ __launch_bounds__(256) void lsm_k(float* __restrict__ o){
  const int row = blockIdx.x * 4 + (threadIdx.x >> 6);
  const int lane = threadIdx.x & 63;
  float* p = o + (size_t)row * NDO + lane * 4;
  float4 v = *(const float4*)p;
  float mx = fmaxf(fmaxf(v.x, v.y), fmaxf(v.z, v.w));
#pragma unroll
  for (int q = 32; q; q >>= 1) mx = fmaxf(mx, __shfl_xor(mx, q));
  float e = expf(v.x - mx) + expf(v.y - mx) + expf(v.z - mx) + expf(v.w - mx);
#pragma unroll
  for (int q = 32; q; q >>= 1) e += __shfl_xor(e, q);
  const float lse = mx + logf(e);
  v.x -= lse; v.y -= lse; v.z -= lse; v.w -= lse;
  *(float4*)p = v;
}

// ---------------- launcher ----------------------------------------------------
extern "C" void kernel_launch(void* const* d_in, const int* in_sizes, int n_in,
                              void* d_out, int out_size, void* d_ws, size_t ws_size,
                              hipStream_t stream)
{
  (void)in_sizes; (void)n_in; (void)out_size; (void)ws_size;
  const float* x      = (const float*)d_in[0];
  const float* enc_w  = (const float*)d_in[1];
  const float* enc_b  = (const float*)d_in[2];
  const float* dec_w  = (const float*)d_in[3];
  const float* dec_b  = (const float*)d_in[4];
  const float* ln_s   = (const float*)d_in[5];
  const float* ln_b   = (const float*)d_in[6];
  const float* lam_re = (const float*)d_in[7];
  const float* lam_im = (const float*)d_in[8];
  const float* p_re   = (const float*)d_in[9];
  const float* p_im   = (const float*)d_in[10];
  const float* b_re   = (const float*)d_in[11];
  const float* b_im   = (const float*)d_in[12];
  const float* c_re   = (const float*)d_in[13];
  const float* c_im   = (const float*)d_in[14];
  const float* lstep  = (const float*)d_in[15];
  const float* d_par  = (const float*)d_in[16];
  const float* out_w  = (const float*)d_in[17];
  const float* out_b  = (const float*)d_in[18];

  // workspace layout (bytes):
  //   h      f32 [BL][512]         64 MB @ 0
  //   abf    bf16 staging          32 MB @ 64M   (x_bf16 / z_bf16 / h_bf16)
  //   zT     bf16 [B][H][L]        32 MB @ 96M
  //   yT     bf16 [B][H][L]        32 MB @ 128M
  //   Kd     f32x2 [4][512][4096]  64 MB @ 160M
  char* ws = (char*)d_ws;
  float*  hbuf = (float*)(ws);
  u16*    abf  = (u16*)  (ws + (size_t)67108864);
  u16*    zT   = (u16*)  (ws + (size_t)67108864 + 33554432);
  u16*    yT   = (u16*)  (ws + (size_t)67108864 + 2*33554432);
  float2* Kd   = (float2*)(ws + (size_t)67108864 + 3*33554432);
  float*  outp = (float*)d_out;

  // 1) x -> bf16
  f32_to_bf16_k<<<dim3(BL*KDIM/8/256), 256, 0, stream>>>(x, abf, BL*KDIM/8);
  // 2) DPLR kernels -> Kd (all layers)
  kd_kernel<<<dim3(NLAY*DH), 256, 0, stream>>>(lam_re, lam_im, p_re, p_im,
                                               b_re, b_im, c_re, c_im, lstep, Kd);
  // 3) encoder GEMM: h = x @ enc_w + enc_b
  gemm_k<false,false><<<dim3(BL/128, DH/128, 1), 256, 0, stream>>>(
      abf, enc_w, enc_b, nullptr, hbuf, BL, DH);
  // 4) layers
  for (int i = 0; i < NLAY; i++){
    ln_k<<<dim3(BL/4), 256, 0, stream>>>(hbuf, ln_s + i*DH, ln_b + i*DH, abf);
    transp_k<<<dim3(SL/64, DH/64, NB), 256, 0, stream>>>(abf, zT);
    s4conv_k<<<dim3((NB/2)*DH), 256, 0, stream>>>(
        zT, Kd + (size_t)i*DH*4096, d_par + i*DH, yT);
    gemm_k<true,true><<<dim3(SL/128, DH/128, NB), 256, 0, stream>>>(
        yT, out_w + (size_t)i*DH*DH, out_b + i*DH, hbuf, hbuf, SL, DH);
  }
  // 5) decoder + log_softmax
  f32_to_bf16_k<<<dim3(BL*DH/8/256), 256, 0, stream>>>(hbuf, abf, BL*DH/8);
  gemm_k<false,false><<<dim3(BL/128, NDO/128, 1), 256, 0, stream>>>(
      abf, dec_w, dec_b, nullptr, outp, BL, NDO);
  lsm_k<<<dim3(BL/4), 256, 0, stream>>>(outp);
}

// Round 2
// 848.690 us; speedup vs baseline: 1.1735x; 1.1735x over previous
//
#include <hip/hip_runtime.h>
#include <hip/hip_bf16.h>

// ---------------- problem constants ----------------
#define NLAY 4
#define DH   512
#define NST  64
#define NB   16
#define SL   2048
#define NDO  256
#define BL   (NB*SL)      // 32768 rows
#define KDIM 512
#define TWOPI 6.283185307179586476925287

typedef unsigned short u16;
typedef __attribute__((ext_vector_type(8))) short  short8v;   // 8 bf16 (4 VGPR) MFMA frag
typedef __attribute__((ext_vector_type(8))) unsigned short ushort8v;
typedef __attribute__((ext_vector_type(4))) float  f32x4;

#define RCPF(x) __builtin_amdgcn_rcpf(x)

// ---------------- small helpers ----------------
__device__ __forceinline__ float bf2f(u16 v){
  union { unsigned u; float f; } x; x.u = ((unsigned)v) << 16; return x.f;
}
__device__ __forceinline__ u16 f2bf(float f){
  union { float f; unsigned u; } x; x.f = f;
  unsigned u = x.u;
  unsigned r = u + 0x7fffu + ((u >> 16) & 1u);   // RNE
  return (u16)(r >> 16);
}
__device__ __forceinline__ void cmulw(float& xr, float& xi, float wr, float wi){
  float tr = xr*wr - xi*wi;
  xi = fmaf(xr, wi, xi*wr);
  xr = tr;
}
__device__ __forceinline__ float gelu_fast(float v){
  const float c0 = 0.7978845608028654f;
  float u = c0 * fmaf(0.044715f, v*v*v, v);
  // 0.5v(1+tanh(u)) == v / (1 + e^{-2u});  rcp(inf)=0 handles v << 0
  return v * RCPF(1.0f + __expf(-2.0f * u));
}

// ---------------- DFT-16 in registers (radix-4 x radix-4), natural in/out ----
template<int SGN>
__device__ __forceinline__ void dft4w(float& r0, float& i0, float& r1, float& i1,
                                      float& r2, float& i2, float& r3, float& i3){
  const float t0r = r0 + r2, t0i = i0 + i2;
  const float t1r = r0 - r2, t1i = i0 - i2;
  const float t2r = r1 + r3, t2i = i1 + i3;
  const float t3r = r1 - r3, t3i = i1 - i3;
  r0 = t0r + t2r; i0 = t0i + t2i;
  r2 = t0r - t2r; i2 = t0i - t2i;
  if (SGN < 0){ r1 = t1r + t3i; i1 = t1i - t3r; r3 = t1r - t3i; i3 = t1i + t3r; }
  else        { r1 = t1r - t3i; i1 = t1i + t3r; r3 = t1r + t3i; i3 = t1i - t3r; }
}

template<int SGN>
__device__ __forceinline__ void dft16(float* re, float* im){
#pragma unroll
  for (int b = 0; b < 4; b++)
    dft4w<SGN>(re[b], im[b], re[4+b], im[4+b], re[8+b], im[8+b], re[12+b], im[12+b]);
  const float C1 = 0.92387953251128675613f, S1_ = 0.38268343236508977172f;
  const float C2 = 0.70710678118654752440f;
  const float sg = (SGN < 0) ? -1.f : 1.f;
  cmulw(re[5],  im[5],   C1,  sg*S1_);
  cmulw(re[9],  im[9],   C2,  sg*C2);
  cmulw(re[13], im[13],  S1_, sg*C1);
  cmulw(re[6],  im[6],   C2,  sg*C2);
  cmulw(re[10], im[10],  0.f, sg*1.f);
  cmulw(re[14], im[14], -C2,  sg*C2);
  cmulw(re[7],  im[7],   S1_, sg*C1);
  cmulw(re[11], im[11], -C2,  sg*C2);
  cmulw(re[15], im[15], -C1,  sg*(-S1_));
#pragma unroll
  for (int c = 0; c < 4; c++)
    dft4w<SGN>(re[4*c], im[4*c], re[4*c+1], im[4*c+1], re[4*c+2], im[4*c+2], re[4*c+3], im[4*c+3]);
  float tr_, ti_;
#define SWP(A,B) tr_=re[A]; re[A]=re[B]; re[B]=tr_; ti_=im[A]; im[A]=im[B]; im[B]=ti_;
  SWP(1,4) SWP(2,8) SWP(3,12) SWP(6,9) SWP(7,13) SWP(11,14)
#undef SWP
}

// LDS padding: all three stage patterns <=2-way bank conflicts
__device__ __forceinline__ int cxpad(int i){ return i + (i >> 4) + ((i >> 8) << 1); }
#define CXSZ 4384

// forward 4096-pt DIF radix-16
__device__ __forceinline__ void fwd4096(float* re, float* im, float2* cx, int t){
  dft16<-1>(re, im);
  const float a0 = -(float)(TWOPI/4096.0) * (float)t;
#pragma unroll
  for (int k = 0; k < 16; k++){
    if (k){ float sn = __sinf(a0*(float)k), cs = __cosf(a0*(float)k); cmulw(re[k], im[k], cs, sn); }
    cx[cxpad(t + 256*k)] = make_float2(re[k], im[k]);
  }
  __syncthreads();
  const int k1 = t >> 4, m2 = t & 15;
  const int b2 = k1*256 + m2;
#pragma unroll
  for (int j = 0; j < 16; j++){ float2 v = cx[cxpad(b2 + 16*j)]; re[j] = v.x; im[j] = v.y; }
  dft16<-1>(re, im);
  const float b0 = -(float)(TWOPI/256.0) * (float)m2;
#pragma unroll
  for (int k = 0; k < 16; k++){
    if (k){ float sn = __sinf(b0*(float)k), cs = __cosf(b0*(float)k); cmulw(re[k], im[k], cs, sn); }
    cx[cxpad(b2 + 16*k)] = make_float2(re[k], im[k]);
  }
  __syncthreads();
#pragma unroll
  for (int j = 0; j < 16; j++){ float2 v = cx[cxpad(16*t + j)]; re[j] = v.x; im[j] = v.y; }
  dft16<-1>(re, im);
}

// inverse: input = values at positions 16t+k3, output time y[t+256j] (unscaled)
__device__ __forceinline__ void inv4096(float* re, float* im, float2* cx, int t){
  dft16<1>(re, im);
#pragma unroll
  for (int j = 0; j < 16; j++) cx[cxpad(16*t + j)] = make_float2(re[j], im[j]);
  __syncthreads();
  const int k1 = t >> 4, m2 = t & 15;
  const int b2 = k1*256 + m2;
  const float b0 = (float)(TWOPI/256.0) * (float)m2;
#pragma unroll
  for (int k = 0; k < 16; k++){
    float2 v = cx[cxpad(b2 + 16*k)];
    re[k] = v.x; im[k] = v.y;
    if (k){ float sn = __sinf(b0*(float)k), cs = __cosf(b0*(float)k); cmulw(re[k], im[k], cs, sn); }
  }
  dft16<1>(re, im);
#pragma unroll
  for (int j = 0; j < 16; j++) cx[cxpad(b2 + 16*j)] = make_float2(re[j], im[j]);
  __syncthreads();
  const float a0 = (float)(TWOPI/4096.0) * (float)t;
#pragma unroll
  for (int k = 0; k < 16; k++){
    float2 v = cx[cxpad(t + 256*k)];
    re[k] = v.x; im[k] = v.y;
    if (k){ float sn = __sinf(a0*(float)k), cs = __cosf(a0*(float)k); cmulw(re[k], im[k], cs, sn); }
  }
  dft16<1>(re, im);
}

// ---------------- prep: per-(lay,h,n) Woodbury weights ----------------
__global__ __launch_bounds__(256) void prep_k(
  const float* __restrict__ lam_re, const float* __restrict__ lam_im,
  const float* __restrict__ p_re,  const float* __restrict__ p_im,
  const float* __restrict__ b_re,  const float* __restrict__ b_im,
  const float* __restrict__ c_re,  const float* __restrict__ c_im,
  float4* __restrict__ cwA, float4* __restrict__ cwB, float* __restrict__ cwS)
{
  const int i = blockIdx.x * 256 + threadIdx.x;   // < NLAY*DH*NST
  const float lr = lam_re[i], li = lam_im[i];
  const float pr = p_re[i],  pi = p_im[i];
  const float br = b_re[i],  bi = b_im[i];
  const float cr = c_re[i],  ci = c_im[i];
  cwA[i] = make_float4(lr, li, cr*br + ci*bi, cr*bi - ci*br);                  // Lam, conj(C)*B
  cwB[i] = make_float4(cr*pr + ci*pi, cr*pi - ci*pr, pr*br + pi*bi, pr*bi - pi*br); // cC*P, cP*B
  cwS[i] = pr*pr + pi*pi;                                                      // conj(P)*P (real)
}

// ---------------- Cauchy/Woodbury generating function -> at_roots -----------
// grid (8, DH, NLAY): one freq per thread, no LDS. Writes linear at_roots into
// the lower half of each (lay,h) Kd block.
__global__ __launch_bounds__(256) void cauchy_k(
    const float4* __restrict__ cwA, const float4* __restrict__ cwB,
    const float* __restrict__ cwS, const float* __restrict__ lstep,
    float2* __restrict__ Kd)
{
  const int t = threadIdx.x;
  const int h = blockIdx.y, lay = blockIdx.z;
  const int l = blockIdx.x * 256 + t;
  const int wb = (lay*DH + h) * NST;
  const float stp = expf(lstep[lay*DH + h]);
  const float tw0 = 2.0f / stp;

  const float th = (float)(TWOPI/2048.0) * (float)l;
  const float sn = sinf(th), cs = cosf(th);   // precise (l=1024 near-singular)
  const float omr = cs, omi = -sn;            // Omega = exp(-i th)
  const float a1r = 1.f - omr, a1i = -omi;    // 1 - Omega
  const float a2r = 1.f + omr, a2i =  omi;    // 1 + Omega
  const float inv2 = RCPF(fmaf(a2r, a2r, a2i*a2i));
  const float gr = tw0 * fmaf(a1r, a2r,  a1i*a2i) * inv2;
  const float gi = tw0 * fmaf(a1i, a2r, -a1r*a2i) * inv2;
  const float clr = 2.f * a2r * inv2, cli = -2.f * a2i * inv2;   // c = 2/(1+Om)

  float k00r=0.f,k00i=0.f,k01r=0.f,k01i=0.f,k10r=0.f,k10i=0.f,k11r=0.f,k11i=0.f;
#pragma unroll 4
  for (int n = 0; n < NST; n++){
    const float4 A  = cwA[wb + n];
    const float4 Bv = cwB[wb + n];
    const float w11 = cwS[wb + n];
    const float dr = gr - A.x, di = gi - A.y;
    const float s = RCPF(fmaf(dr, dr, di*di));
    const float ivr = dr * s, ivi = -di * s;                // 1/(g-Lam)
    k00r = fmaf(A.z, ivr, fmaf(-A.w, ivi, k00r)); k00i = fmaf(A.z, ivi, fmaf(A.w, ivr, k00i));
    k01r = fmaf(Bv.x,ivr, fmaf(-Bv.y,ivi, k01r)); k01i = fmaf(Bv.x,ivi, fmaf(Bv.y,ivr, k01i));
    k10r = fmaf(Bv.z,ivr, fmaf(-Bv.w,ivi, k10r)); k10i = fmaf(Bv.z,ivi, fmaf(Bv.w,ivr, k10i));
    k11r = fmaf(w11, ivr, k11r);                  k11i = fmaf(w11, ivi, k11i);
  }
  const float d1r = 1.f + k11r, d1i = k11i;
  const float idn = RCPF(fmaf(d1r, d1r, d1i*d1i));
  const float wr = k01r*k10r - k01i*k10i, wi = k01r*k10i + k01i*k10r;  // k01*k10
  const float vr = fmaf(wr, d1r,  wi*d1i) * idn;
  const float vi = fmaf(wi, d1r, -wr*d1i) * idn;                       // /(1+k11)
  const float sr = k00r - vr, si = k00i - vi;
  Kd[(size_t)(lay*DH + h) * 4096 + l] =
      make_float2(clr*sr - cli*si, fmaf(clr, si, cli*sr));
}

// ---------------- ifft2048 + fwd fft4096 -> Kd (digit-rev order) -------------
__global__ __launch_bounds__(256) void kdfft_k(float2* __restrict__ Kd){
  __shared__ float  ar[SL], ai[SL];
  __shared__ float2 cx[CXSZ];
  const int t = threadIdx.x;
  const size_t base = (size_t)blockIdx.x * 4096;
#pragma unroll
  for (int q = 0; q < 8; q++){
    const int l = t + 256*q;
    float2 v = Kd[base + l];
    const int brv = __brev((unsigned)l) >> 21;    // 11-bit reverse
    ar[brv] = v.x; ai[brv] = v.y;
  }
  __syncthreads();

  // inverse DFT-2048 (radix-2 DIT, bit-reversed input -> natural K)
  for (int s = 0; s < 11; s++){
    const int half = 1 << s;
    const float fac = (float)(TWOPI) / (float)(2 << s);
#pragma unroll
    for (int q = 0; q < 4; q++){
      const int v = t + 256*q;
      const int pos = v & (half - 1);
      const int i0 = ((v >> s) << (s+1)) + pos;
      const int i1 = i0 + half;
      const float ang = fac * (float)pos;
      const float wc = __cosf(ang), ws = __sinf(ang);   // e^{+i ang}
      const float xr = ar[i1], xi = ai[i1];
      const float tr = wc*xr - ws*xi, ti = fmaf(wc, xi, ws*xr);
      const float ur_ = ar[i0], ui_ = ai[i0];
      ar[i0] = ur_ + tr; ai[i0] = ui_ + ti;
      ar[i1] = ur_ - tr; ai[i1] = ui_ - ti;
    }
    __syncthreads();
  }

  // K (real, scaled 1/2048), zero-pad to 4096, forward DIF -> Kd
  float re[16], im[16];
#pragma unroll
  for (int j = 0; j < 16; j++){
    re[j] = (j < 8) ? ar[t + 256*j] * (1.0f/2048.f) : 0.f;
    im[j] = 0.f;
  }
  fwd4096(re, im, cx, t);
  float2* kp = Kd + base + 16*t;
#pragma unroll
  for (int k = 0; k < 16; k += 2)
    *(float4*)(kp + k) = make_float4(re[k], im[k], re[k+1], im[k+1]);
}

// ---------------- weight convert+transpose f32[K][N] -> bf16[N][K] -----------
__global__ __launch_bounds__(256) void wconv_k(const float* __restrict__ src,
    u16* __restrict__ dst, int K, int N){
  __shared__ u16 tile[64][72];
  const size_t mb = (size_t)blockIdx.z * K * N;
  const int k0 = blockIdx.x * 64, n0 = blockIdx.y * 64;
  const int r = threadIdx.x >> 2, c4 = (threadIdx.x & 3) * 16;
  const float* s = src + mb + (size_t)(k0 + r) * N + n0 + c4;
  float4 f0 = *(const float4*)s, f1 = *(const float4*)(s+4);
  float4 f2 = *(const float4*)(s+8), f3 = *(const float4*)(s+12);
  tile[c4+0][r]=f2bf(f0.x); tile[c4+1][r]=f2bf(f0.y); tile[c4+2][r]=f2bf(f0.z); tile[c4+3][r]=f2bf(f0.w);
  tile[c4+4][r]=f2bf(f1.x); tile[c4+5][r]=f2bf(f1.y); tile[c4+6][r]=f2bf(f1.z); tile[c4+7][r]=f2bf(f1.w);
  tile[c4+8][r]=f2bf(f2.x); tile[c4+9][r]=f2bf(f2.y); tile[c4+10][r]=f2bf(f2.z); tile[c4+11][r]=f2bf(f2.w);
  tile[c4+12][r]=f2bf(f3.x); tile[c4+13][r]=f2bf(f3.y); tile[c4+14][r]=f2bf(f3.z); tile[c4+15][r]=f2bf(f3.w);
  __syncthreads();
  u16* d = dst + mb + (size_t)(n0 + r) * K + k0 + c4;
  *(ushort8v*)d       = *(const ushort8v*)&tile[r][c4];
  *(ushort8v*)(d + 8) = *(const ushort8v*)&tile[r][c4 + 8];
}

// ---------------- LayerNorm (f32 in, bf16 out, [b,l,h] layout) ---------------
__global__ __launch_bounds__(256) void ln_k(const float* __restrict__ hsrc,
    const float* __restrict__ gam, const float* __restrict__ bet,
    u16* __restrict__ zdst){
  const int row = blockIdx.x * 4 + (threadIdx.x >> 6);
  const int lane = threadIdx.x & 63;
  const float* p = hsrc + (size_t)row * DH + lane * 8;
  float4 a = *(const float4*)p, b = *(const float4*)(p + 4);
  float s  = (a.x + a.y) + (a.z + a.w) + (b.x + b.y) + (b.z + b.w);
  float sq = a.x*a.x + a.y*a.y + a.z*a.z + a.w*a.w
           + b.x*b.x + b.y*b.y + b.z*b.z + b.w*b.w;
#pragma unroll
  for (int o = 32; o; o >>= 1){ s += __shfl_xor(s, o); sq += __shfl_xor(sq, o); }
  const float mu = s * (1.0f/DH);
  const float rs = rsqrtf(sq * (1.0f/DH) - mu*mu + 1e-6f);
  const float4 g0 = *(const float4*)(gam + lane*8), g1 = *(const float4*)(gam + lane*8 + 4);
  const float4 t0 = *(const float4*)(bet + lane*8), t1 = *(const float4*)(bet + lane*8 + 4);
  ushort8v o;
  o[0] = f2bf(fmaf((a.x - mu)*rs, g0.x, t0.x));
  o[1] = f2bf(fmaf((a.y - mu)*rs, g0.y, t0.y));
  o[2] = f2bf(fmaf((a.z - mu)*rs, g0.z, t0.z));
  o[3] = f2bf(fmaf((a.w - mu)*rs, g0.w, t0.w));
  o[4] = f2bf(fmaf((b.x - mu)*rs, g1.x, t1.x));
  o[5] = f2bf(fmaf((b.y - mu)*rs, g1.y, t1.y));
  o[6] = f2bf(fmaf((b.z - mu)*rs, g1.z, t1.z));
  o[7] = f2bf(fmaf((b.w - mu)*rs, g1.w, t1.w));
  *(ushort8v*)(zdst + (size_t)row * DH + lane*8) = o;
}

// ---------------- bf16 transpose [b,l,h] -> [b,h,l] --------------------------
__global__ __launch_bounds__(256) void transp_k(const u16* __restrict__ z,
                                                u16* __restrict__ zT){
  __shared__ u16 tile[64][72];
  const int bz = blockIdx.z;
  const int l0 = blockIdx.x * 64, h0 = blockIdx.y * 64;
  const int r = threadIdx.x >> 2, c4 = (threadIdx.x & 3) * 16;
  const u16* src = z + ((size_t)bz * SL + l0 + r) * DH + h0 + c4;
  ushort8v v0 = *(const ushort8v*)src;
  ushort8v v1 = *(const ushort8v*)(src + 8);
#pragma unroll
  for (int j = 0; j < 8; j++){ tile[c4 + j][r] = v0[j]; tile[c4 + 8 + j][r] = v1[j]; }
  __syncthreads();
  u16* dst = zT + ((size_t)bz * DH + h0 + r) * SL + l0 + c4;
  *(ushort8v*)dst       = *(const ushort8v*)&tile[r][c4];
  *(ushort8v*)(dst + 8) = *(const ushort8v*)&tile[r][c4 + 8];
}

// ---------------- S4 FFT convolution + D*u + GELU ----------------------------
__global__ __launch_bounds__(256) void s4conv_k(
    const u16* __restrict__ zT, const float2* __restrict__ Kd,
    const float* __restrict__ dpar, u16* __restrict__ yT)
{
  __shared__ float2 cx[CXSZ];
  const int t = threadIdx.x;
  const int wg = blockIdx.x;          // 8 pairs * 512 channels
  const int h = wg & 511, bp = wg >> 9;
  const u16* r1 = zT + ((size_t)(2*bp) * DH + h) * SL;
  const u16* r2 = r1 + (size_t)DH * SL;
  float ur1[8], ur2[8];
  float re[16], im[16];
#pragma unroll
  for (int j = 0; j < 8; j++){
    ur1[j] = bf2f(r1[t + 256*j]);
    ur2[j] = bf2f(r2[t + 256*j]);
    re[j] = ur1[j]; im[j] = ur2[j];
  }
#pragma unroll
  for (int j = 8; j < 16; j++){ re[j] = 0.f; im[j] = 0.f; }

  fwd4096(re, im, cx, t);

  const float2* kp = Kd + (size_t)h * 4096 + 16*t;
#pragma unroll
  for (int k = 0; k < 16; k += 2){
    float4 w2 = *(const float4*)(kp + k);
    cmulw(re[k],   im[k],   w2.x, w2.y);
    cmulw(re[k+1], im[k+1], w2.z, w2.w);
  }

  inv4096(re, im, cx, t);

  const float Dv = dpar[h];
  u16* y1 = yT + ((size_t)(2*bp) * DH + h) * SL;
  u16* y2 = y1 + (size_t)DH * SL;
#pragma unroll
  for (int j = 0; j < 8; j++){
    float v1 = fmaf(re[j], (1.0f/4096.f), Dv * ur1[j]);
    float v2 = fmaf(im[j], (1.0f/4096.f), Dv * ur2[j]);
    y1[t + 256*j] = f2bf(gelu_fast(v1));
    y2[t + 256*j] = f2bf(gelu_fast(v2));
  }
}

// ---------------- bf16 MFMA GEMM, 128x128 tile, BK=32 ------------------------
// AMODE: 0 = bf16 [M][K]; 1 = bf16 [K][M] batched (blockIdx.z); 2 = f32 [M][K].
// Wt is bf16 [N][K]. grid: x = n-tile (fast, A-tile L2 reuse), y = m-tile.
template<int AMODE, bool RESID>
__global__ __launch_bounds__(256) void gemm_k(
    const void* __restrict__ Aptr, const u16* __restrict__ Wt,
    const float* __restrict__ bias,
    const float* __restrict__ resid, float* __restrict__ Cout,
    int Mb, int N)
{
  __shared__ u16 As[128][40];
  __shared__ u16 Bs[128][40];
  const int t = threadIdx.x;
  const int n0 = blockIdx.x * 128, m0 = blockIdx.y * 128, bb = blockIdx.z;
  const int lane = t & 63, wv = t >> 6;
  const int wm = (wv >> 1) * 64, wn = (wv & 1) * 64;
  f32x4 acc[4][4];
#pragma unroll
  for (int mi = 0; mi < 4; mi++)
#pragma unroll
    for (int ni = 0; ni < 4; ni++) acc[mi][ni] = {0.f, 0.f, 0.f, 0.f};

  const u16*  Ab = (const u16*)Aptr;
  const float* Af = (const float*)Aptr;
  const size_t Abase = (AMODE == 1) ? (size_t)bb * KDIM * Mb : 0;

  for (int k0 = 0; k0 < KDIM; k0 += 32){
    __syncthreads();
    if (AMODE == 1){
      const int kk = t >> 3, ch = t & 7;
      const u16* srca = Ab + Abase + (size_t)(k0 + kk) * Mb + m0 + ch*16;
      ushort8v v0 = *(const ushort8v*)srca;
      ushort8v v1 = *(const ushort8v*)(srca + 8);
      const int col = (kk & 7) | (((kk >> 3) ^ (ch & 3)) << 3);
#pragma unroll
      for (int i = 0; i < 8; i++){
        As[ch*16 + i][col]     = (u16)v0[i];
        As[ch*16 + 8 + i][col] = (u16)v1[i];
      }
    } else if (AMODE == 0){
      const int r = t >> 1, kh = (t & 1) << 4;
      const u16* srca = Ab + (size_t)(m0 + r) * KDIM + k0 + kh;
      ushort8v v0 = *(const ushort8v*)srca;
      ushort8v v1 = *(const ushort8v*)(srca + 8);
      const int s3 = (r >> 4) & 3;
      const int c0 = (((kh >> 3) ^ s3) << 3);
      const int c1 = ((((kh >> 3) + 1) ^ s3) << 3);
      *(ushort8v*)&As[r][c0] = v0;
      *(ushort8v*)&As[r][c1] = v1;
    } else {
      const int r = t >> 1, kh = (t & 1) << 4;
      const float* sf = Af + (size_t)(m0 + r) * KDIM + k0 + kh;
      float4 f0 = *(const float4*)sf,     f1 = *(const float4*)(sf + 4);
      float4 f2 = *(const float4*)(sf+8), f3 = *(const float4*)(sf + 12);
      ushort8v v0, v1;
      v0[0]=f2bf(f0.x); v0[1]=f2bf(f0.y); v0[2]=f2bf(f0.z); v0[3]=f2bf(f0.w);
      v0[4]=f2bf(f1.x); v0[5]=f2bf(f1.y); v0[6]=f2bf(f1.z); v0[7]=f2bf(f1.w);
      v1[0]=f2bf(f2.x); v1[1]=f2bf(f2.y); v1[2]=f2bf(f2.z); v1[3]=f2bf(f2.w);
      v1[4]=f2bf(f3.x); v1[5]=f2bf(f3.y); v1[6]=f2bf(f3.z); v1[7]=f2bf(f3.w);
      const int s3 = (r >> 4) & 3;
      const int c0 = (((kh >> 3) ^ s3) << 3);
      const int c1 = ((((kh >> 3) + 1) ^ s3) << 3);
      *(ushort8v*)&As[r][c0] = v0;
      *(ushort8v*)&As[r][c1] = v1;
    }
    {
      const int r = t >> 1, kh = (t & 1) << 4;
      const u16* srcb = Wt + (size_t)(n0 + r) * KDIM + k0 + kh;
      ushort8v v0 = *(const ushort8v*)srcb;
      ushort8v v1 = *(const ushort8v*)(srcb + 8);
      const int s3 = (r >> 4) & 3;
      const int c0 = (((kh >> 3) ^ s3) << 3);
      const int c1 = ((((kh >> 3) + 1) ^ s3) << 3);
      *(ushort8v*)&Bs[r][c0] = v0;
      *(ushort8v*)&Bs[r][c1] = v1;
    }
    __syncthreads();

    const int ko = (lane >> 4) * 8;
    const int fr = lane & 15;
    short8v af[4], bf[4];
#pragma unroll
    for (int mi = 0; mi < 4; mi++){
      const int col = (((ko >> 3) ^ (((wm >> 4) + mi) & 3)) << 3);
      af[mi] = *(const short8v*)&As[wm + mi*16 + fr][col];
    }
#pragma unroll
    for (int ni = 0; ni < 4; ni++){
      const int col = (((ko >> 3) ^ (((wn >> 4) + ni) & 3)) << 3);
      bf[ni] = *(const short8v*)&Bs[wn + ni*16 + fr][col];
    }
#pragma unroll
    for (int mi = 0; mi < 4; mi++)
#pragma unroll
      for (int ni = 0; ni < 4; ni++)
        acc[mi][ni] = __builtin_amdgcn_mfma_f32_16x16x32_bf16(af[mi], bf[ni], acc[mi][ni], 0, 0, 0);
  }

  // epilogue: C/D layout col=lane&15, row=(lane>>4)*4+q
  const int fr = lane & 15;
  const int rq = (lane >> 4) * 4;
#pragma unroll
  for (int mi = 0; mi < 4; mi++){
#pragma unroll
    for (int ni = 0; ni < 4; ni++){
      const int gn = n0 + wn + ni*16 + fr;
      const float bs = bias[gn];
#pragma unroll
      for (int q = 0; q < 4; q++){
        const int gm = m0 + wm + mi*16 + rq + q;
        const size_t idx = ((size_t)bb * Mb + gm) * N + gn;
        float v = acc[mi][ni][q] + bs;
        if (RESID) v += resid[idx];
        Cout[idx] = v;
      }
    }
  }
}

// ---------------- in-place log-softmax over rows of 256 ----------------------
__global__ __launch_bounds__(256) void lsm_k(float* __restrict__ o){
  const int row = blockIdx.x * 4 + (threadIdx.x >> 6);
  const int lane = threadIdx.x & 63;
  float* p = o + (size_t)row * NDO + lane * 4;
  float4 v = *(const float4*)p;
  float mx = fmaxf(fmaxf(v.x, v.y), fmaxf(v.z, v.w));
#pragma unroll
  for (int q = 32; q; q >>= 1) mx = fmaxf(mx, __shfl_xor(mx, q));
  float e = __expf(v.x - mx) + __expf(v.y - mx) + __expf(v.z - mx) + __expf(v.w - mx);
#pragma unroll
  for (int q = 32; q; q >>= 1) e += __shfl_xor(e, q);
  const float lse = mx + __logf(e);
  v.x -= lse; v.y -= lse; v.z -= lse; v.w -= lse;
  *(float4*)p = v;
}

// ---------------- launcher ----------------------------------------------------
extern "C" void kernel_launch(void* const* d_in, const int* in_sizes, int n_in,
                              void* d_out, int out_size, void* d_ws, size_t ws_size,
                              hipStream_t stream)
{
  (void)in_sizes; (void)n_in; (void)out_size; (void)ws_size;
  const float* x      = (const float*)d_in[0];
  const float* enc_w  = (const float*)d_in[1];
  const float* enc_b  = (const float*)d_in[2];
  const float* dec_w  = (const float*)d_in[3];
  const float* dec_b  = (const float*)d_in[4];
  const float* ln_s   = (const float*)d_in[5];
  const float* ln_b   = (const float*)d_in[6];
  const float* lam_re = (const float*)d_in[7];
  const float* lam_im = (const float*)d_in[8];
  const float* p_re   = (const float*)d_in[9];
  const float* p_im   = (const float*)d_in[10];
  const float* b_re   = (const float*)d_in[11];
  const float* b_im   = (const float*)d_in[12];
  const float* c_re   = (const float*)d_in[13];
  const float* c_im   = (const float*)d_in[14];
  const float* lstep  = (const float*)d_in[15];
  const float* d_par  = (const float*)d_in[16];
  const float* out_w  = (const float*)d_in[17];
  const float* out_b  = (const float*)d_in[18];

  // workspace layout (bytes):
  //   hbuf f32 [BL][512]          64 MB @ 0
  //   abf  bf16 [b,l,h]           32 MB @ 64M
  //   zT   bf16 [B][H][L]         32 MB @ 96M
  //   yT   bf16 [B][H][L]         32 MB @ 128M
  //   Kd   f32x2 [4][512][4096]   64 MB @ 160M
  //   Wt   bf16 weights [N][K]   ~2.8 MB @ 224M  (enc, out0..3, dec)
  char* ws = (char*)d_ws;
  float*  hbuf = (float*)(ws);
  u16*    abf  = (u16*)  (ws + (size_t)67108864);
  u16*    zT   = (u16*)  (ws + (size_t)67108864 + 33554432);
  u16*    yT   = (u16*)  (ws + (size_t)67108864 + 2*33554432);
  float2* Kd   = (float2*)(ws + (size_t)67108864 + 3*33554432);
  u16*    Wt   = (u16*)  (ws + (size_t)67108864 + 3*33554432 + 67108864);
  u16*    WtEnc = Wt;                         // 512*512
  u16*    WtOut = Wt + 262144;                // 4 * 512*512
  u16*    WtDec = Wt + 262144*5;              // 256*512
  float*  outp = (float*)d_out;

  // Cauchy weights live in d_out scratch (overwritten by dec gemm at the end)
  float4* cwA = (float4*)d_out;               // 131072 float4
  float4* cwB = cwA + 131072;
  float*  cwS = (float*)(cwB + 131072);

  // 1) weight prep
  prep_k<<<dim3(NLAY*DH*NST/256), 256, 0, stream>>>(lam_re, lam_im, p_re, p_im,
                                                    b_re, b_im, c_re, c_im, cwA, cwB, cwS);
  wconv_k<<<dim3(8, 8, 1), 256, 0, stream>>>(enc_w, WtEnc, KDIM, DH);
  wconv_k<<<dim3(8, 8, NLAY), 256, 0, stream>>>(out_w, WtOut, KDIM, DH);
  wconv_k<<<dim3(8, 4, 1), 256, 0, stream>>>(dec_w, WtDec, KDIM, NDO);
  // 2) DPLR kernels
  cauchy_k<<<dim3(8, DH, NLAY), 256, 0, stream>>>(cwA, cwB, cwS, lstep, Kd);
  kdfft_k<<<dim3(NLAY*DH), 256, 0, stream>>>(Kd);
  // 3) encoder GEMM: h = x @ enc_w + enc_b  (f32 A, in-staging bf16 convert)
  gemm_k<2,false><<<dim3(DH/128, BL/128, 1), 256, 0, stream>>>(
      x, WtEnc, enc_b, nullptr, hbuf, BL, DH);
  // 4) layers
  for (int i = 0; i < NLAY; i++){
    ln_k<<<dim3(BL/4), 256, 0, stream>>>(hbuf, ln_s + i*DH, ln_b + i*DH, abf);
    transp_k<<<dim3(SL/64, DH/64, NB), 256, 0, stream>>>(abf, zT);
    s4conv_k<<<dim3((NB/2)*DH), 256, 0, stream>>>(
        zT, Kd + (size_t)i*DH*4096, d_par + i*DH, yT);
    gemm_k<1,true><<<dim3(DH/128, SL/128, NB), 256, 0, stream>>>(
        yT, WtOut + (size_t)i*262144, out_b + i*DH, hbuf, hbuf, SL, DH);
  }
  // 5) decoder (f32 A) + log_softmax
  gemm_k<2,false><<<dim3(NDO/128, BL/128, 1), 256, 0, stream>>>(
      hbuf, WtDec, dec_b, nullptr, outp, BL, NDO);
  lsm_k<<<dim3(BL/4), 256, 0, stream>>>(outp);
}

// Round 4
// 838.245 us; speedup vs baseline: 1.1881x; 1.0125x over previous
//
#include <hip/hip_runtime.h>
#include <hip/hip_bf16.h>

// ---------------- problem constants ----------------
#define NLAY 4
#define DH   512
#define NST  64
#define NB   16
#define SL   2048
#define NDO  256
#define BL   (NB*SL)      // 32768 rows
#define KDIM 512
#define TWOPI 6.283185307179586476925287

typedef unsigned short u16;
typedef __attribute__((ext_vector_type(8))) short  short8v;   // 8 bf16 (4 VGPR) MFMA frag
typedef __attribute__((ext_vector_type(8))) unsigned short ushort8v;
typedef __attribute__((ext_vector_type(4))) float  f32x4;

#define RCPF(x) __builtin_amdgcn_rcpf(x)

// ---------------- small helpers ----------------
__device__ __forceinline__ float bf2f(u16 v){
  union { unsigned u; float f; } x; x.u = ((unsigned)v) << 16; return x.f;
}
__device__ __forceinline__ u16 f2bf(float f){
  union { float f; unsigned u; } x; x.f = f;
  unsigned u = x.u;
  unsigned r = u + 0x7fffu + ((u >> 16) & 1u);   // RNE
  return (u16)(r >> 16);
}
__device__ __forceinline__ void cmulw(float& xr, float& xi, float wr, float wi){
  float tr = xr*wr - xi*wi;
  xi = fmaf(xr, wi, xi*wr);
  xr = tr;
}
__device__ __forceinline__ float gelu_fast(float v){
  const float c0 = 0.7978845608028654f;
  float u = c0 * fmaf(0.044715f, v*v*v, v);
  // 0.5v(1+tanh(u)) == v / (1 + e^{-2u});  rcp(inf)=0 handles v << 0
  return v * RCPF(1.0f + __expf(-2.0f * u));
}

// ---------------- DFT-16 in registers (radix-4 x radix-4), natural in/out ----
template<int SGN>
__device__ __forceinline__ void dft4w(float& r0, float& i0, float& r1, float& i1,
                                      float& r2, float& i2, float& r3, float& i3){
  const float t0r = r0 + r2, t0i = i0 + i2;
  const float t1r = r0 - r2, t1i = i0 - i2;
  const float t2r = r1 + r3, t2i = i1 + i3;
  const float t3r = r1 - r3, t3i = i1 - i3;
  r0 = t0r + t2r; i0 = t0i + t2i;
  r2 = t0r - t2r; i2 = t0i - t2i;
  if (SGN < 0){ r1 = t1r + t3i; i1 = t1i - t3r; r3 = t1r - t3i; i3 = t1i + t3r; }
  else        { r1 = t1r - t3i; i1 = t1i + t3r; r3 = t1r + t3i; i3 = t1i - t3r; }
}

template<int SGN>
__device__ __forceinline__ void dft16(float* re, float* im){
#pragma unroll
  for (int b = 0; b < 4; b++)
    dft4w<SGN>(re[b], im[b], re[4+b], im[4+b], re[8+b], im[8+b], re[12+b], im[12+b]);
  const float C1 = 0.92387953251128675613f, S1_ = 0.38268343236508977172f;
  const float C2 = 0.70710678118654752440f;
  const float sg = (SGN < 0) ? -1.f : 1.f;
  cmulw(re[5],  im[5],   C1,  sg*S1_);
  cmulw(re[9],  im[9],   C2,  sg*C2);
  cmulw(re[13], im[13],  S1_, sg*C1);
  cmulw(re[6],  im[6],   C2,  sg*C2);
  cmulw(re[10], im[10],  0.f, sg*1.f);
  cmulw(re[14], im[14], -C2,  sg*C2);
  cmulw(re[7],  im[7],   S1_, sg*C1);
  cmulw(re[11], im[11], -C2,  sg*C2);
  cmulw(re[15], im[15], -C1,  sg*(-S1_));
#pragma unroll
  for (int c = 0; c < 4; c++)
    dft4w<SGN>(re[4*c], im[4*c], re[4*c+1], im[4*c+1], re[4*c+2], im[4*c+2], re[4*c+3], im[4*c+3]);
  float tr_, ti_;
#define SWP(A,B) tr_=re[A]; re[A]=re[B]; re[B]=tr_; ti_=im[A]; im[A]=im[B]; im[B]=ti_;
  SWP(1,4) SWP(2,8) SWP(3,12) SWP(6,9) SWP(7,13) SWP(11,14)
#undef SWP
}

// LDS padding: all three stage patterns <=2-way bank conflicts
__device__ __forceinline__ int cxpad(int i){ return i + (i >> 4) + ((i >> 8) << 1); }
#define CXSZ 4384

// forward 4096-pt DIF radix-16
__device__ __forceinline__ void fwd4096(float* re, float* im, float2* cx, int t){
  dft16<-1>(re, im);
  const float a0 = -(float)(TWOPI/4096.0) * (float)t;
#pragma unroll
  for (int k = 0; k < 16; k++){
    if (k){ float sn = __sinf(a0*(float)k), cs = __cosf(a0*(float)k); cmulw(re[k], im[k], cs, sn); }
    cx[cxpad(t + 256*k)] = make_float2(re[k], im[k]);
  }
  __syncthreads();
  const int k1 = t >> 4, m2 = t & 15;
  const int b2 = k1*256 + m2;
#pragma unroll
  for (int j = 0; j < 16; j++){ float2 v = cx[cxpad(b2 + 16*j)]; re[j] = v.x; im[j] = v.y; }
  dft16<-1>(re, im);
  const float b0 = -(float)(TWOPI/256.0) * (float)m2;
#pragma unroll
  for (int k = 0; k < 16; k++){
    if (k){ float sn = __sinf(b0*(float)k), cs = __cosf(b0*(float)k); cmulw(re[k], im[k], cs, sn); }
    cx[cxpad(b2 + 16*k)] = make_float2(re[k], im[k]);
  }
  __syncthreads();
#pragma unroll
  for (int j = 0; j < 16; j++){ float2 v = cx[cxpad(16*t + j)]; re[j] = v.x; im[j] = v.y; }
  dft16<-1>(re, im);
}

// inverse: input = values at positions 16t+k3, output time y[t+256j] (unscaled)
__device__ __forceinline__ void inv4096(float* re, float* im, float2* cx, int t){
  dft16<1>(re, im);
#pragma unroll
  for (int j = 0; j < 16; j++) cx[cxpad(16*t + j)] = make_float2(re[j], im[j]);
  __syncthreads();
  const int k1 = t >> 4, m2 = t & 15;
  const int b2 = k1*256 + m2;
  const float b0 = (float)(TWOPI/256.0) * (float)m2;
#pragma unroll
  for (int k = 0; k < 16; k++){
    float2 v = cx[cxpad(b2 + 16*k)];
    re[k] = v.x; im[k] = v.y;
    if (k){ float sn = __sinf(b0*(float)k), cs = __cosf(b0*(float)k); cmulw(re[k], im[k], cs, sn); }
  }
  dft16<1>(re, im);
#pragma unroll
  for (int j = 0; j < 16; j++) cx[cxpad(b2 + 16*j)] = make_float2(re[j], im[j]);
  __syncthreads();
  const float a0 = (float)(TWOPI/4096.0) * (float)t;
#pragma unroll
  for (int k = 0; k < 16; k++){
    float2 v = cx[cxpad(t + 256*k)];
    re[k] = v.x; im[k] = v.y;
    if (k){ float sn = __sinf(a0*(float)k), cs = __cosf(a0*(float)k); cmulw(re[k], im[k], cs, sn); }
  }
  dft16<1>(re, im);
}

// ---------------- prep: per-(lay,h,n) Woodbury weights ----------------
__global__ __launch_bounds__(256) void prep_k(
  const float* __restrict__ lam_re, const float* __restrict__ lam_im,
  const float* __restrict__ p_re,  const float* __restrict__ p_im,
  const float* __restrict__ b_re,  const float* __restrict__ b_im,
  const float* __restrict__ c_re,  const float* __restrict__ c_im,
  float4* __restrict__ cwA, float4* __restrict__ cwB, float* __restrict__ cwS)
{
  const int i = blockIdx.x * 256 + threadIdx.x;   // < NLAY*DH*NST
  const float lr = lam_re[i], li = lam_im[i];
  const float pr = p_re[i],  pi = p_im[i];
  const float br = b_re[i],  bi = b_im[i];
  const float cr = c_re[i],  ci = c_im[i];
  cwA[i] = make_float4(lr, li, cr*br + ci*bi, cr*bi - ci*br);                  // Lam, conj(C)*B
  cwB[i] = make_float4(cr*pr + ci*pi, cr*pi - ci*pr, pr*br + pi*bi, pr*bi - pi*br); // cC*P, cP*B
  cwS[i] = pr*pr + pi*pi;                                                      // conj(P)*P (real)
}

// ---------------- Cauchy/Woodbury generating function -> at_roots -----------
// g = i*gi with gi = (2/step)*tan(theta/2);  c = 1 + i*tan(theta/2).
// 4 freqs per thread (l, l+512, l+1024, l+1536). grid (2, DH, NLAY).
__global__ __launch_bounds__(256) void cauchy_k(
    const float4* __restrict__ cwA, const float4* __restrict__ cwB,
    const float* __restrict__ cwS, const float* __restrict__ lstep,
    float2* __restrict__ Kd)
{
  const int t = threadIdx.x;
  const int h = blockIdx.y, lay = blockIdx.z;
  const int lb = blockIdx.x * 256 + t;
  const int wb = (lay*DH + h) * NST;
  const float tw0 = 2.0f * expf(-lstep[lay*DH + h]);   // 2/step

  float T[4], gi[4];
#pragma unroll
  for (int j = 0; j < 4; j++){
    float sn, cs;
    sincosf((float)(TWOPI/4096.0) * (float)(lb + 512*j), &sn, &cs);  // theta/2
    T[j] = sn * RCPF(cs);          // tan(theta/2); large-finite at l=1024
    gi[j] = tw0 * T[j];
  }

  float k00r[4]={0,0,0,0}, k00i[4]={0,0,0,0};
  float k01r[4]={0,0,0,0}, k01i[4]={0,0,0,0};
  float k10r[4]={0,0,0,0}, k10i[4]={0,0,0,0};
  float k11r[4]={0,0,0,0}, k11i[4]={0,0,0,0};

#pragma unroll 2
  for (int n = 0; n < NST; n++){
    const float4 A  = cwA[wb + n];
    const float4 Bv = cwB[wb + n];
    const float w11 = cwS[wb + n];
    const float nlr = -A.x;            // -lam_re  (real part of g - Lam)
    const float dr2 = A.x * A.x;
#pragma unroll
    for (int j = 0; j < 4; j++){
      const float di = gi[j] - A.y;
      const float sI = RCPF(fmaf(di, di, dr2));
      const float ivr = nlr * sI, ivi = -di * sI;      // 1/(g-Lam)
      k00r[j] = fmaf(A.z,  ivr, fmaf(-A.w,  ivi, k00r[j]));
      k00i[j] = fmaf(A.z,  ivi, fmaf( A.w,  ivr, k00i[j]));
      k01r[j] = fmaf(Bv.x, ivr, fmaf(-Bv.y, ivi, k01r[j]));
      k01i[j] = fmaf(Bv.x, ivi, fmaf( Bv.y, ivr, k01i[j]));
      k10r[j] = fmaf(Bv.z, ivr, fmaf(-Bv.w, ivi, k10r[j]));
      k10i[j] = fmaf(Bv.z, ivi, fmaf( Bv.w, ivr, k10i[j]));
      k11r[j] = fmaf(w11,  ivr, k11r[j]);
      k11i[j] = fmaf(w11,  ivi, k11i[j]);
    }
  }

  float2* kp = Kd + (size_t)(lay*DH + h) * 4096;
#pragma unroll
  for (int j = 0; j < 4; j++){
    const float d1r = 1.f + k11r[j], d1i = k11i[j];
    const float idn = RCPF(fmaf(d1r, d1r, d1i*d1i));
    const float wr = k01r[j]*k10r[j] - k01i[j]*k10i[j];
    const float wi = k01r[j]*k10i[j] + k01i[j]*k10r[j];    // k01*k10
    const float vr = fmaf(wr, d1r,  wi*d1i) * idn;
    const float vi = fmaf(wi, d1r, -wr*d1i) * idn;         // /(1+k11)
    const float sr = k00r[j] - vr, si = k00i[j] - vi;
    // at_roots = (1 + i*T) * (sr + i*si)
    kp[lb + 512*j] = make_float2(fmaf(-T[j], si, sr), fmaf(T[j], sr, si));
  }
}

// ---------------- ifft2048 + fwd fft4096 -> Kd (digit-rev order) -------------
__global__ __launch_bounds__(256) void kdfft_k(float2* __restrict__ Kd){
  __shared__ float  ar[SL], ai[SL];
  __shared__ float2 cx[CXSZ];
  const int t = threadIdx.x;
  const size_t base = (size_t)blockIdx.x * 4096;
#pragma unroll
  for (int q = 0; q < 8; q++){
    const int l = t + 256*q;
    float2 v = Kd[base + l];
    const int brv = __brev((unsigned)l) >> 21;    // 11-bit reverse
    ar[brv] = v.x; ai[brv] = v.y;
  }
  __syncthreads();

  // inverse DFT-2048 (radix-2 DIT, bit-reversed input -> natural K)
  for (int s = 0; s < 11; s++){
    const int half = 1 << s;
    const float fac = (float)(TWOPI) / (float)(2 << s);
#pragma unroll
    for (int q = 0; q < 4; q++){
      const int v = t + 256*q;
      const int pos = v & (half - 1);
      const int i0 = ((v >> s) << (s+1)) + pos;
      const int i1 = i0 + half;
      const float ang = fac * (float)pos;
      const float wc = __cosf(ang), ws = __sinf(ang);   // e^{+i ang}
      const float xr = ar[i1], xi = ai[i1];
      const float tr = wc*xr - ws*xi, ti = fmaf(wc, xi, ws*xr);
      const float ur_ = ar[i0], ui_ = ai[i0];
      ar[i0] = ur_ + tr; ai[i0] = ui_ + ti;
      ar[i1] = ur_ - tr; ai[i1] = ui_ - ti;
    }
    __syncthreads();
  }

  // K (real, scaled 1/2048), zero-pad to 4096, forward DIF -> Kd
  float re[16], im[16];
#pragma unroll
  for (int j = 0; j < 16; j++){
    re[j] = (j < 8) ? ar[t + 256*j] * (1.0f/2048.f) : 0.f;
    im[j] = 0.f;
  }
  fwd4096(re, im, cx, t);
  float2* kp = Kd + base + 16*t;
#pragma unroll
  for (int k = 0; k < 16; k += 2)
    *(float4*)(kp + k) = make_float4(re[k], im[k], re[k+1], im[k+1]);
}

// ---------------- weight convert+transpose f32[K][N] -> bf16[N][K] -----------
__global__ __launch_bounds__(256) void wconv_k(const float* __restrict__ src,
    u16* __restrict__ dst, int K, int N){
  __shared__ u16 tile[64][72];
  const size_t mb = (size_t)blockIdx.z * K * N;
  const int k0 = blockIdx.x * 64, n0 = blockIdx.y * 64;
  const int r = threadIdx.x >> 2, c4 = (threadIdx.x & 3) * 16;
  const float* s = src + mb + (size_t)(k0 + r) * N + n0 + c4;
  float4 f0 = *(const float4*)s, f1 = *(const float4*)(s+4);
  float4 f2 = *(const float4*)(s+8), f3 = *(const float4*)(s+12);
  tile[c4+0][r]=f2bf(f0.x); tile[c4+1][r]=f2bf(f0.y); tile[c4+2][r]=f2bf(f0.z); tile[c4+3][r]=f2bf(f0.w);
  tile[c4+4][r]=f2bf(f1.x); tile[c4+5][r]=f2bf(f1.y); tile[c4+6][r]=f2bf(f1.z); tile[c4+7][r]=f2bf(f1.w);
  tile[c4+8][r]=f2bf(f2.x); tile[c4+9][r]=f2bf(f2.y); tile[c4+10][r]=f2bf(f2.z); tile[c4+11][r]=f2bf(f2.w);
  tile[c4+12][r]=f2bf(f3.x); tile[c4+13][r]=f2bf(f3.y); tile[c4+14][r]=f2bf(f3.z); tile[c4+15][r]=f2bf(f3.w);
  __syncthreads();
  u16* d = dst + mb + (size_t)(n0 + r) * K + k0 + c4;
  *(ushort8v*)d       = *(const ushort8v*)&tile[r][c4];
  *(ushort8v*)(d + 8) = *(const ushort8v*)&tile[r][c4 + 8];
}

// ---------------- fused LayerNorm + transpose: f32 [b,l,h] -> bf16 [b,h,l] ---
// 32-l x 512-h tile per block. The transposed LDS tile is chunk-swizzled with
// s(h) = ((h>>1) + (h>>6)) & 3, applied IDENTICALLY on write (column
// c = r ^ (s<<3)) and read (chunk og holds logical l-group og ^ s).
#define LTILE 32
__device__ __forceinline__ int lnswz(int h){ return ((h >> 1) + (h >> 6)) & 3; }

__global__ __launch_bounds__(256) void lnt_k(const float* __restrict__ hsrc,
    const float* __restrict__ gam, const float* __restrict__ bet,
    u16* __restrict__ zT){
  __shared__ u16 tile[DH][LTILE];
  __shared__ float smu[LTILE], srs[LTILE];
  const int t = threadIdx.x;
  const int b = blockIdx.y, l0 = blockIdx.x * LTILE;
  const int r = t >> 3, hb = (t & 7) * 64;
  const float* p = hsrc + ((size_t)b * SL + l0 + r) * DH + hb;
  float s = 0.f, sq = 0.f;
#pragma unroll
  for (int j4 = 0; j4 < 16; j4++){
    float4 v = *(const float4*)(p + j4*4);
    s  += (v.x + v.y) + (v.z + v.w);
    sq += v.x*v.x + v.y*v.y + v.z*v.z + v.w*v.w;
    const int h0 = hb + j4*4;
    tile[h0+0][r ^ (lnswz(h0+0) << 3)] = f2bf(v.x);
    tile[h0+1][r ^ (lnswz(h0+1) << 3)] = f2bf(v.y);
    tile[h0+2][r ^ (lnswz(h0+2) << 3)] = f2bf(v.z);
    tile[h0+3][r ^ (lnswz(h0+3) << 3)] = f2bf(v.w);
  }
  s  += __shfl_xor(s, 1);  sq += __shfl_xor(sq, 1);
  s  += __shfl_xor(s, 2);  sq += __shfl_xor(sq, 2);
  s  += __shfl_xor(s, 4);  sq += __shfl_xor(sq, 4);
  if ((t & 7) == 0){
    const float mu = s * (1.0f/DH);
    smu[r] = mu;
    srs[r] = rsqrtf(sq * (1.0f/DH) - mu*mu + 1e-6f);
  }
  __syncthreads();

#pragma unroll
  for (int hh = 0; hh < 2; hh++){
    const int h = t + hh*256;
    const float g = gam[h], be = bet[h];
    const int sw = lnswz(h);
    u16* dst = zT + ((size_t)b * DH + h) * SL + l0;
#pragma unroll
    for (int og = 0; og < 4; og++){
      const int lg = og ^ sw;                    // logical l-group in this chunk
      ushort8v v = *(const ushort8v*)&tile[h][og*8];
      const float4 m0 = *(const float4*)&smu[lg*8];
      const float4 m1 = *(const float4*)&smu[lg*8 + 4];
      const float4 r0 = *(const float4*)&srs[lg*8];
      const float4 r1 = *(const float4*)&srs[lg*8 + 4];
      ushort8v o;
      o[0] = f2bf(fmaf(bf2f((u16)v[0]) - m0.x, r0.x*g, be));
      o[1] = f2bf(fmaf(bf2f((u16)v[1]) - m0.y, r0.y*g, be));
      o[2] = f2bf(fmaf(bf2f((u16)v[2]) - m0.z, r0.z*g, be));
      o[3] = f2bf(fmaf(bf2f((u16)v[3]) - m0.w, r0.w*g, be));
      o[4] = f2bf(fmaf(bf2f((u16)v[4]) - m1.x, r1.x*g, be));
      o[5] = f2bf(fmaf(bf2f((u16)v[5]) - m1.y, r1.y*g, be));
      o[6] = f2bf(fmaf(bf2f((u16)v[6]) - m1.z, r1.z*g, be));
      o[7] = f2bf(fmaf(bf2f((u16)v[7]) - m1.w, r1.w*g, be));
      *(ushort8v*)(dst + lg*8) = o;
    }
  }
}

// ---------------- S4 FFT convolution + D*u + GELU ----------------------------
__global__ __launch_bounds__(256) void s4conv_k(
    const u16* __restrict__ zT, const float2* __restrict__ Kd,
    const float* __restrict__ dpar, u16* __restrict__ yT)
{
  __shared__ float2 cx[CXSZ];
  const int t = threadIdx.x;
  const int wg = blockIdx.x;          // 8 pairs * 512 channels
  const int h = wg & 511, bp = wg >> 9;
  const u16* r1 = zT + ((size_t)(2*bp) * DH + h) * SL;
  const u16* r2 = r1 + (size_t)DH * SL;
  float ur1[8], ur2[8];
  float re[16], im[16];
#pragma unroll
  for (int j = 0; j < 8; j++){
    ur1[j] = bf2f(r1[t + 256*j]);
    ur2[j] = bf2f(r2[t + 256*j]);
    re[j] = ur1[j]; im[j] = ur2[j];
  }
#pragma unroll
  for (int j = 8; j < 16; j++){ re[j] = 0.f; im[j] = 0.f; }

  fwd4096(re, im, cx, t);

  const float2* kp = Kd + (size_t)h * 4096 + 16*t;
#pragma unroll
  for (int k = 0; k < 16; k += 2){
    float4 w2 = *(const float4*)(kp + k);
    cmulw(re[k],   im[k],   w2.x, w2.y);
    cmulw(re[k+1], im[k+1], w2.z, w2.w);
  }

  inv4096(re, im, cx, t);

  const float Dv = dpar[h];
  u16* y1 = yT + ((size_t)(2*bp) * DH + h) * SL;
  u16* y2 = y1 + (size_t)DH * SL;
#pragma unroll
  for (int j = 0; j < 8; j++){
    float v1 = fmaf(re[j], (1.0f/4096.f), Dv * ur1[j]);
    float v2 = fmaf(im[j], (1.0f/4096.f), Dv * ur2[j]);
    y1[t + 256*j] = f2bf(gelu_fast(v1));
    y2[t + 256*j] = f2bf(gelu_fast(v2));
  }
}

// ---------------- bf16 MFMA GEMM, 128x128 tile, BK=32 ------------------------
// AMODE: 0 = bf16 [M][K]; 1 = bf16 [K][M] batched (blockIdx.z); 2 = f32 [M][K].
// Wt is bf16 [N][K]. grid: x = n-tile (fast, A-tile L2 reuse), y = m-tile.
template<int AMODE, bool RESID>
__global__ __launch_bounds__(256) void gemm_k(
    const void* __restrict__ Aptr, const u16* __restrict__ Wt,
    const float* __restrict__ bias,
    const float* __restrict__ resid, float* __restrict__ Cout,
    int Mb, int N)
{
  __shared__ u16 As[128][40];
  __shared__ u16 Bs[128][40];
  const int t = threadIdx.x;
  const int n0 = blockIdx.x * 128, m0 = blockIdx.y * 128, bb = blockIdx.z;
  const int lane = t & 63, wv = t >> 6;
  const int wm = (wv >> 1) * 64, wn = (wv & 1) * 64;
  f32x4 acc[4][4];
#pragma unroll
  for (int mi = 0; mi < 4; mi++)
#pragma unroll
    for (int ni = 0; ni < 4; ni++) acc[mi][ni] = {0.f, 0.f, 0.f, 0.f};

  const u16*  Ab = (const u16*)Aptr;
  const float* Af = (const float*)Aptr;
  const size_t Abase = (AMODE == 1) ? (size_t)bb * KDIM * Mb : 0;

  for (int k0 = 0; k0 < KDIM; k0 += 32){
    __syncthreads();
    if (AMODE == 1){
      const int kk = t >> 3, ch = t & 7;
      const u16* srca = Ab + Abase + (size_t)(k0 + kk) * Mb + m0 + ch*16;
      ushort8v v0 = *(const ushort8v*)srca;
      ushort8v v1 = *(const ushort8v*)(srca + 8);
      const int col = (kk & 7) | (((kk >> 3) ^ (ch & 3)) << 3);
#pragma unroll
      for (int i = 0; i < 8; i++){
        As[ch*16 + i][col]     = (u16)v0[i];
        As[ch*16 + 8 + i][col] = (u16)v1[i];
      }
    } else if (AMODE == 0){
      const int r = t >> 1, kh = (t & 1) << 4;
      const u16* srca = Ab + (size_t)(m0 + r) * KDIM + k0 + kh;
      ushort8v v0 = *(const ushort8v*)srca;
      ushort8v v1 = *(const ushort8v*)(srca + 8);
      const int s3 = (r >> 4) & 3;
      const int c0 = (((kh >> 3) ^ s3) << 3);
      const int c1 = ((((kh >> 3) + 1) ^ s3) << 3);
      *(ushort8v*)&As[r][c0] = v0;
      *(ushort8v*)&As[r][c1] = v1;
    } else {
      const int r = t >> 1, kh = (t & 1) << 4;
      const float* sf = Af + (size_t)(m0 + r) * KDIM + k0 + kh;
      float4 f0 = *(const float4*)sf,     f1 = *(const float4*)(sf + 4);
      float4 f2 = *(const float4*)(sf+8), f3 = *(const float4*)(sf + 12);
      ushort8v v0, v1;
      v0[0]=f2bf(f0.x); v0[1]=f2bf(f0.y); v0[2]=f2bf(f0.z); v0[3]=f2bf(f0.w);
      v0[4]=f2bf(f1.x); v0[5]=f2bf(f1.y); v0[6]=f2bf(f1.z); v0[7]=f2bf(f1.w);
      v1[0]=f2bf(f2.x); v1[1]=f2bf(f2.y); v1[2]=f2bf(f2.z); v1[3]=f2bf(f2.w);
      v1[4]=f2bf(f3.x); v1[5]=f2bf(f3.y); v1[6]=f2bf(f3.z); v1[7]=f2bf(f3.w);
      const int s3 = (r >> 4) & 3;
      const int c0 = (((kh >> 3) ^ s3) << 3);
      const int c1 = ((((kh >> 3) + 1) ^ s3) << 3);
      *(ushort8v*)&As[r][c0] = v0;
      *(ushort8v*)&As[r][c1] = v1;
    }
    {
      const int r = t >> 1, kh = (t & 1) << 4;
      const u16* srcb = Wt + (size_t)(n0 + r) * KDIM + k0 + kh;
      ushort8v v0 = *(const ushort8v*)srcb;
      ushort8v v1 = *(const ushort8v*)(srcb + 8);
      const int s3 = (r >> 4) & 3;
      const int c0 = (((kh >> 3) ^ s3) << 3);
      const int c1 = ((((kh >> 3) + 1) ^ s3) << 3);
      *(ushort8v*)&Bs[r][c0] = v0;
      *(ushort8v*)&Bs[r][c1] = v1;
    }
    __syncthreads();

    const int ko = (lane >> 4) * 8;
    const int fr = lane & 15;
    short8v af[4], bf[4];
#pragma unroll
    for (int mi = 0; mi < 4; mi++){
      const int col = (((ko >> 3) ^ (((wm >> 4) + mi) & 3)) << 3);
      af[mi] = *(const short8v*)&As[wm + mi*16 + fr][col];
    }
#pragma unroll
    for (int ni = 0; ni < 4; ni++){
      const int col = (((ko >> 3) ^ (((wn >> 4) + ni) & 3)) << 3);
      bf[ni] = *(const short8v*)&Bs[wn + ni*16 + fr][col];
    }
#pragma unroll
    for (int mi = 0; mi < 4; mi++)
#pragma unroll
      for (int ni = 0; ni < 4; ni++)
        acc[mi][ni] = __builtin_amdgcn_mfma_f32_16x16x32_bf16(af[mi], bf[ni], acc[mi][ni], 0, 0, 0);
  }

  // epilogue: C/D layout col=lane&15, row=(lane>>4)*4+q
  const int fr = lane & 15;
  const int rq = (lane >> 4) * 4;
#pragma unroll
  for (int mi = 0; mi < 4; mi++){
#pragma unroll
    for (int ni = 0; ni < 4; ni++){
      const int gn = n0 + wn + ni*16 + fr;
      const float bs = bias[gn];
#pragma unroll
      for (int q = 0; q < 4; q++){
        const int gm = m0 + wm + mi*16 + rq + q;
        const size_t idx = ((size_t)bb * Mb + gm) * N + gn;
        float v = acc[mi][ni][q] + bs;
        if (RESID) v += resid[idx];
        Cout[idx] = v;
      }
    }
  }
}

// ---------------- in-place log-softmax over rows of 256 ----------------------
__global__ __launch_bounds__(256) void lsm_k(float* __restrict__ o){
  const int row = blockIdx.x * 4 + (threadIdx.x >> 6);
  const int lane = threadIdx.x & 63;
  float* p = o + (size_t)row * NDO + lane * 4;
  float4 v = *(const float4*)p;
  float mx = fmaxf(fmaxf(v.x, v.y), fmaxf(v.z, v.w));
#pragma unroll
  for (int q = 32; q; q >>= 1) mx = fmaxf(mx, __shfl_xor(mx, q));
  float e = __expf(v.x - mx) + __expf(v.y - mx) + __expf(v.z - mx) + __expf(v.w - mx);
#pragma unroll
  for (int q = 32; q; q >>= 1) e += __shfl_xor(e, q);
  const float lse = mx + __logf(e);
  v.x -= lse; v.y -= lse; v.z -= lse; v.w -= lse;
  *(float4*)p = v;
}

// ---------------- launcher ----------------------------------------------------
extern "C" void kernel_launch(void* const* d_in, const int* in_sizes, int n_in,
                              void* d_out, int out_size, void* d_ws, size_t ws_size,
                              hipStream_t stream)
{
  (void)in_sizes; (void)n_in; (void)out_size; (void)ws_size;
  const float* x      = (const float*)d_in[0];
  const float* enc_w  = (const float*)d_in[1];
  const float* enc_b  = (const float*)d_in[2];
  const float* dec_w  = (const float*)d_in[3];
  const float* dec_b  = (const float*)d_in[4];
  const float* ln_s   = (const float*)d_in[5];
  const float* ln_b   = (const float*)d_in[6];
  const float* lam_re = (const float*)d_in[7];
  const float* lam_im = (const float*)d_in[8];
  const float* p_re   = (const float*)d_in[9];
  const float* p_im   = (const float*)d_in[10];
  const float* b_re   = (const float*)d_in[11];
  const float* b_im   = (const float*)d_in[12];
  const float* c_re   = (const float*)d_in[13];
  const float* c_im   = (const float*)d_in[14];
  const float* lstep  = (const float*)d_in[15];
  const float* d_par  = (const float*)d_in[16];
  const float* out_w  = (const float*)d_in[17];
  const float* out_b  = (const float*)d_in[18];

  // workspace layout (bytes):
  //   hbuf f32 [BL][512]          64 MB @ 0
  //   (spare)                     32 MB @ 64M
  //   zT   bf16 [B][H][L]         32 MB @ 96M
  //   yT   bf16 [B][H][L]         32 MB @ 128M
  //   Kd   f32x2 [4][512][4096]   64 MB @ 160M
  //   Wt   bf16 weights [N][K]   ~2.8 MB @ 224M  (enc, out0..3, dec)
  char* ws = (char*)d_ws;
  float*  hbuf = (float*)(ws);
  u16*    zT   = (u16*)  (ws + (size_t)67108864 + 33554432);
  u16*    yT   = (u16*)  (ws + (size_t)67108864 + 2*33554432);
  float2* Kd   = (float2*)(ws + (size_t)67108864 + 3*33554432);
  u16*    Wt   = (u16*)  (ws + (size_t)67108864 + 3*33554432 + 67108864);
  u16*    WtEnc = Wt;                         // 512*512
  u16*    WtOut = Wt + 262144;                // 4 * 512*512
  u16*    WtDec = Wt + 262144*5;              // 256*512
  float*  outp = (float*)d_out;

  // Cauchy weights live in d_out scratch (overwritten by dec gemm at the end)
  float4* cwA = (float4*)d_out;               // 131072 float4
  float4* cwB = cwA + 131072;
  float*  cwS = (float*)(cwB + 131072);

  // 1) weight prep
  prep_k<<<dim3(NLAY*DH*NST/256), 256, 0, stream>>>(lam_re, lam_im, p_re, p_im,
                                                    b_re, b_im, c_re, c_im, cwA, cwB, cwS);
  wconv_k<<<dim3(8, 8, 1), 256, 0, stream>>>(enc_w, WtEnc, KDIM, DH);
  wconv_k<<<dim3(8, 8, NLAY), 256, 0, stream>>>(out_w, WtOut, KDIM, DH);
  wconv_k<<<dim3(8, 4, 1), 256, 0, stream>>>(dec_w, WtDec, KDIM, NDO);
  // 2) DPLR kernels
  cauchy_k<<<dim3(2, DH, NLAY), 256, 0, stream>>>(cwA, cwB, cwS, lstep, Kd);
  kdfft_k<<<dim3(NLAY*DH), 256, 0, stream>>>(Kd);
  // 3) encoder GEMM: h = x @ enc_w + enc_b  (f32 A, in-staging bf16 convert)
  gemm_k<2,false><<<dim3(DH/128, BL/128, 1), 256, 0, stream>>>(
      x, WtEnc, enc_b, nullptr, hbuf, BL, DH);
  // 4) layers
  for (int i = 0; i < NLAY; i++){
    lnt_k<<<dim3(SL/LTILE, NB), 256, 0, stream>>>(hbuf, ln_s + i*DH, ln_b + i*DH, zT);
    s4conv_k<<<dim3((NB/2)*DH), 256, 0, stream>>>(
        zT, Kd + (size_t)i*DH*4096, d_par + i*DH, yT);
    gemm_k<1,true><<<dim3(DH/128, SL/128, NB), 256, 0, stream>>>(
        yT, WtOut + (size_t)i*262144, out_b + i*DH, hbuf, hbuf, SL, DH);
  }
  // 5) decoder (f32 A) + log_softmax
  gemm_k<2,false><<<dim3(NDO/128, BL/128, 1), 256, 0, stream>>>(
      hbuf, WtDec, dec_b, nullptr, outp, BL, NDO);
  lsm_k<<<dim3(BL/4), 256, 0, stream>>>(outp);
}